// Round 4
// baseline (8556.384 us; speedup 1.0000x reference)
//
#include <hip/hip_runtime.h>
#include <cstdint>

#define SEQ   2048
#define BATCH 128
#define IN    64
#define HID   256
#define OUTD  64
#define G4    1024

// Per-thread W_hh slots: slot s = jj*8+i -> (row 8*(t>>2)+i, col-chunk (t&3)+4*jj, 8 cols)
// s in [0,40): pinned VGPR; [40,46): LDS; [46,64): streamed from L2 (x2 copies)
#define NPIN  40
#define NLDSW 6
#define NSTRW 18

// ws layout (dword offsets)
#define OFF_REG   0
#define SZ_REG    (NPIN*512*4)            // 81920
#define OFF_LDSW  (OFF_REG+SZ_REG)        // 81920
#define SZ_LDSW   (NLDSW*512*4)           // 12288
#define OFF_STR   (OFF_LDSW+SZ_LDSW)      // 94208
#define SZ_STR1   (NSTRW*512*4)           // 36864 per copy, x2
#define OFF_WOUT  (OFF_STR+2*SZ_STR1)     // 167936
#define SZ_WOUT1  8192                    // per copy, x2
#define OFF_PATHX (OFF_WOUT+2*SZ_WOUT1)   // 184320
// path A: W_ih row-major flat (for xw precompute), then xW buffer
#define OFF_WIHRM OFF_PATHX
#define SZ_WIHRM  16384
#define OFF_XW    (OFF_WIHRM+SZ_WIHRM)    // 200704 dw (16B aligned)
#define SZ_XW     ((size_t)SEQ*BATCH*G4)  // 268435456 dw
// path B: W_ih in scan layout, x2 copies
#define OFF_WIHB  OFF_PATHX
#define SZ_WIHB1  (16*512*4)              // 32768 per copy, x2

#define TOTAL_A   (OFF_WIHRM+SZ_WIHRM)    // 200704
#define TOTAL_B   (OFF_WIHB+2*SZ_WIHB1)   // 249856
#define NEED_A_BYTES ((size_t)TOTAL_A*4 + SZ_XW*4)

typedef _Float16 f16x2 __attribute__((ext_vector_type(2)));

__device__ __forceinline__ float fexp2(float v) { return __builtin_amdgcn_exp2f(v); }
__device__ __forceinline__ float frcp(float v)  { return __builtin_amdgcn_rcpf(v); }
__device__ __forceinline__ float fsig(float v)  { return frcp(1.0f + fexp2(v * -1.44269504088896f)); }
__device__ __forceinline__ float ftanh_(float v){ return 1.0f - 2.0f * frcp(1.0f + fexp2(v * 2.88539008177793f)); }

__device__ __forceinline__ unsigned int pack2d(float a, float b) {
  unsigned short lo = __builtin_bit_cast(unsigned short, (_Float16)a);
  unsigned short hi = __builtin_bit_cast(unsigned short, (_Float16)b);
  return (unsigned int)lo | ((unsigned int)hi << 16);
}

__device__ __forceinline__ float dot2f(unsigned int w, unsigned int h, float acc) {
#if __has_builtin(__builtin_amdgcn_fdot2)
  return __builtin_amdgcn_fdot2(__builtin_bit_cast(f16x2, w), __builtin_bit_cast(f16x2, h), acc, false);
#else
  f16x2 a = __builtin_bit_cast(f16x2, w), b = __builtin_bit_cast(f16x2, h);
  return acc + (float)a.x * (float)b.x + (float)a.y * (float)b.y;
#endif
}

__device__ __forceinline__ void mac8(uint4 w, uint4 h, float& acc) {
  acc = dot2f(w.x, h.x, acc);
  acc = dot2f(w.y, h.y, acc);
  acc = dot2f(w.z, h.z, acc);
  acc = dot2f(w.w, h.w, acc);
}

// quad_perm DPP cross-lane: xor1 = [1,0,3,2] = 0xB1, xor2 = [2,3,0,1] = 0x4E
__device__ __forceinline__ float dpp_xor1(float v) {
  return __builtin_bit_cast(float, __builtin_amdgcn_mov_dpp(__builtin_bit_cast(int, v), 0xB1, 0xF, 0xF, true));
}
__device__ __forceinline__ float dpp_xor2(float v) {
  return __builtin_bit_cast(float, __builtin_amdgcn_mov_dpp(__builtin_bit_cast(int, v), 0x4E, 0xF, 0xF, true));
}

// ---------------- prep: fp32 weights -> packed f16 in ws ----------------
__global__ void prep_weights(const float* __restrict__ Whh, const float* __restrict__ Wih,
                             const float* __restrict__ Wout, unsigned int* __restrict__ ws,
                             int modeA, int total) {
  int tid = blockIdx.x * 256 + threadIdx.x;
  if (tid >= total) return;
  unsigned int val;
  if (tid < OFF_LDSW) {                                     // pinned W_hh slots 0..39
    int sl = tid >> 11, t = (tid >> 2) & 511, d = tid & 3;
    int jj = sl >> 3, i = sl & 7;
    int row = 8*(t >> 2) + i;
    int col = 8*((t & 3) + 4*jj) + 2*d;
    const float* p = Whh + (size_t)row*HID + col;
    val = pack2d(p[0], p[1]);
  } else if (tid < OFF_STR) {                               // LDS slots 40..45
    int r = tid - OFF_LDSW;
    int v = r >> 11, t = (r >> 2) & 511, d = r & 3;
    int sl = NPIN + v, jj = sl >> 3, i = sl & 7;
    int row = 8*(t >> 2) + i;
    int col = 8*((t & 3) + 4*jj) + 2*d;
    const float* p = Whh + (size_t)row*HID + col;
    val = pack2d(p[0], p[1]);
  } else if (tid < OFF_WOUT) {                              // streamed slots 46..63 (x2)
    int r = (tid - OFF_STR) % SZ_STR1;
    int v = r >> 11, t = (r >> 2) & 511, d = r & 3;
    int sl = NPIN + NLDSW + v, jj = sl >> 3, i = sl & 7;
    int row = 8*(t >> 2) + i;
    int col = 8*((t & 3) + 4*jj) + 2*d;
    const float* p = Whh + (size_t)row*HID + col;
    val = pack2d(p[0], p[1]);
  } else if (tid < OFF_PATHX) {                             // W_out flat (x2)
    int r = (tid - OFF_WOUT) % SZ_WOUT1;
    const float* p = Wout + 2*r;
    val = pack2d(p[0], p[1]);
  } else if (modeA) {                                       // path A: W_ih row-major flat
    int r = tid - OFF_WIHRM;
    const float* p = Wih + 2*r;
    val = pack2d(p[0], p[1]);
  } else {                                                  // path B: W_ih scan layout (x2)
    int r = (tid - OFF_WIHB) % SZ_WIHB1;
    int v = r >> 11, t = (r >> 2) & 511, d = r & 3;
    int ee = v >> 3, i = v & 7;
    int row = 8*(t >> 2) + i;
    int col = 8*((t & 3) + 4*ee) + 2*d;
    const float* p = Wih + (size_t)row*IN + col;
    val = pack2d(p[0], p[1]);
  }
  ws[tid] = val;
}

// ---------------- path A: xW[s,b,g] = x[s,b,:].W_ih[g,:] + bias[g] ----------------
__global__ __launch_bounds__(256) void xw_precompute(
    const float* __restrict__ x, const float* __restrict__ bias,
    const unsigned int* __restrict__ wih_rm, float* __restrict__ xw) {
  const int t = threadIdx.x;
  const size_t m0 = (size_t)blockIdx.x * 128;
  __shared__ __align__(16) unsigned int xls[128*32];
  for (int i = t; i < 128*32; i += 256) {
    float2 v = *(const float2*)(x + (m0 + (size_t)(i >> 5))*IN + 2*(i & 31));
    xls[i] = pack2d(v.x, v.y);
  }
  __syncthreads();
  for (int chunk = 0; chunk < 4; ++chunk) {
    const int n = chunk*256 + t;
    uint4 w[8];
    const uint4* wp = (const uint4*)(wih_rm + (size_t)n*32);
    #pragma unroll
    for (int j = 0; j < 8; ++j) w[j] = wp[j];
    const float bn = bias[n];
    for (int m = 0; m < 128; ++m) {
      float acc = bn;
      const uint4* xp = (const uint4*)(xls + m*32);
      #pragma unroll
      for (int j = 0; j < 8; ++j) mac8(w[j], xp[j], acc);
      xw[(m0 + m)*G4 + n] = acc;
    }
  }
}

// ---------------- scan: one block per batch element, one block per CU ----------------
template<bool USE_XW>
__global__ __launch_bounds__(512, 2) void lstm_scan(
    const float* __restrict__ x, const float* __restrict__ h0, const float* __restrict__ c0,
    const float* __restrict__ bias, const float* __restrict__ b_out,
    const unsigned int* __restrict__ wsbase, const float* __restrict__ xw,
    float* __restrict__ out)
{
  const int b = blockIdx.x, t = threadIdx.x;
  const int q = t >> 2, l = t & 3;

  __shared__ __align__(16) unsigned int wlds[NLDSW*512*4];   // 48 KB
  __shared__ __align__(16) float lin_sh[G4];                 // 4 KB
  __shared__ __align__(16) float bias_sh[G4];                // 4 KB (path B)
  __shared__ __align__(16) unsigned short hs[HID];
  __shared__ __align__(16) unsigned short xs[2][IN];

  const unsigned int* WregS = wsbase + OFF_REG;
  const unsigned int* WldsS = wsbase + OFF_LDSW;
  const unsigned int* WstrS = wsbase + OFF_STR;
  const unsigned short* WoutS = (const unsigned short*)(wsbase + OFF_WOUT);
  const unsigned int* WihB  = wsbase + OFF_WIHB;

  // pinned register weights; asm on scalar temps (named, not indirect)
  uint4 wr[NPIN];
  #pragma unroll
  for (int sl = 0; sl < NPIN; ++sl)
    wr[sl] = *(const uint4*)(WregS + ((size_t)sl*512 + t)*4);
  #pragma unroll
  for (int sl = 0; sl < NPIN; ++sl) {
    unsigned a0 = wr[sl].x, a1 = wr[sl].y, a2 = wr[sl].z, a3 = wr[sl].w;
    asm volatile("" : "+v"(a0), "+v"(a1), "+v"(a2), "+v"(a3));
    wr[sl].x = a0; wr[sl].y = a1; wr[sl].z = a2; wr[sl].w = a3;
  }

  #pragma unroll
  for (int v = 0; v < NLDSW; ++v) {
    int idx = (v*512 + t)*4;
    *(uint4*)(wlds + idx) = *(const uint4*)(WldsS + idx);
  }
  if (!USE_XW) {
    bias_sh[t] = bias[t];
    bias_sh[t + 512] = bias[t + 512];
  }

  float c = 0.0f;
  if (t < HID) {
    c = c0[(size_t)b*HID + t];
    hs[t] = (unsigned short)(pack2d(h0[(size_t)b*HID + t], 0.0f) & 0xffffu);
  } else if (!USE_XW && t < HID + 32) {
    int i = t - HID;
    float2 xx = *(const float2*)(x + (size_t)b*IN + 2*i);
    ((unsigned int*)xs[0])[i] = pack2d(xx.x, xx.y);
  }
  const int o = t >> 3, seg = t & 7;
  const float bo = b_out[o];
  __syncthreads();

  for (int s = 0; s < SEQ; ++s) {
    const int alt = s & 1;
    const int cur = s & 1;
    const unsigned int* strB = WstrS + (size_t)alt*SZ_STR1;
    const unsigned short* woB = WoutS + (size_t)alt*(2*SZ_WOUT1);

    // prefetch xw (path A) / next x (path B) — independent of h, hidden under dots
    float xw0 = 0.f, xw1 = 0.f, xw2 = 0.f, xw3 = 0.f;
    float2 xn = make_float2(0.f, 0.f);
    if (USE_XW) {
      if (t < HID) {
        const float* xwp = xw + ((size_t)s*BATCH + b)*G4 + t;
        xw0 = xwp[0]; xw1 = xwp[256]; xw2 = xwp[512]; xw3 = xwp[768];
      }
    } else {
      if (t >= HID && t < HID + 32) {
        int sn = (s + 1 < SEQ) ? s + 1 : s;
        xn = *(const float2*)(x + ((size_t)sn*BATCH + b)*IN + 2*(t - HID));
      }
    }

    // ---- dot phase: acc[i] = partial(row 8q+i) over this thread's 64 cols ----
    float acc[8] = {0.f,0.f,0.f,0.f,0.f,0.f,0.f,0.f};
    #pragma unroll
    for (int jj = 0; jj < 8; ++jj) {
      const uint4 hv = *(const uint4*)(hs + 8*(l + 4*jj));
      #pragma unroll
      for (int i = 0; i < 8; ++i) {
        const int sl = jj*8 + i;
        uint4 w;
        if (sl < NPIN)              w = wr[sl];
        else if (sl < NPIN + NLDSW) w = *(const uint4*)(wlds + ((sl - NPIN)*512 + t)*4);
        else                        w = *(const uint4*)(strB + ((size_t)(sl - NPIN - NLDSW)*512 + t)*4);
        mac8(w, hv, acc[i]);
      }
    }
    if (!USE_XW) {
      const unsigned int* ihB = WihB + (size_t)alt*SZ_WIHB1;
      #pragma unroll
      for (int ee = 0; ee < 2; ++ee) {
        const uint4 xv = *(const uint4*)(xs[cur] + 8*(l + 4*ee));
        #pragma unroll
        for (int i = 0; i < 8; ++i) {
          uint4 w = *(const uint4*)(ihB + ((size_t)(ee*8 + i)*512 + t)*4);
          mac8(w, xv, acc[i]);
        }
      }
    }

    // ---- reduce partials across the 4-lane col groups (DPP, VALU pipe) ----
    #pragma unroll
    for (int i = 0; i < 8; ++i) {
      acc[i] += dpp_xor1(acc[i]);
      acc[i] += dpp_xor2(acc[i]);
    }
    // lane l publishes rows 8q+2l, 8q+2l+1
    float v0, v1;
    if (l == 0)      { v0 = acc[0]; v1 = acc[1]; }
    else if (l == 1) { v0 = acc[2]; v1 = acc[3]; }
    else if (l == 2) { v0 = acc[4]; v1 = acc[5]; }
    else             { v0 = acc[6]; v1 = acc[7]; }
    *(float2*)&lin_sh[8*q + 2*l] = make_float2(v0, v1);

    // W_out prefetch (L2-hot, consumed after barrier b)
    uint4 wo[4];
    #pragma unroll
    for (int qq = 0; qq < 4; ++qq)
      wo[qq] = *(const uint4*)(woB + (size_t)o*256 + seg*32 + 8*qq);

    __syncthreads();  // (a) lin complete

    if (t < HID) {
      float li  = lin_sh[t]        + (USE_XW ? xw0 : bias_sh[t]);
      float lf  = lin_sh[t + 256]  + (USE_XW ? xw1 : bias_sh[t + 256]);
      float lg  = lin_sh[t + 512]  + (USE_XW ? xw2 : bias_sh[t + 512]);
      float lo_ = lin_sh[t + 768]  + (USE_XW ? xw3 : bias_sh[t + 768]);
      float ig = fsig(li), fg = fsig(lf), gg = ftanh_(lg), og = fsig(lo_);
      c = fg*c + ig*gg;
      float hn = og*ftanh_(c);
      hs[t] = (unsigned short)(pack2d(hn, 0.0f) & 0xffffu);
    } else if (!USE_XW && t < HID + 32) {
      ((unsigned int*)xs[cur ^ 1])[t - HID] = pack2d(xn.x, xn.y);
    }
    __syncthreads();  // (b) h_s published

    // ---- fused readout ----
    float racc = 0.f;
    #pragma unroll
    for (int qq = 0; qq < 4; ++qq) {
      const uint4 hv = *(const uint4*)(hs + seg*32 + 8*qq);
      mac8(wo[qq], hv, racc);
    }
    racc += dpp_xor1(racc);
    racc += dpp_xor2(racc);
    racc += __shfl_xor(racc, 4);
    if (seg == 0) out[((size_t)s*BATCH + b)*OUTD + o] = racc + bo;
  }
}

extern "C" void kernel_launch(void* const* d_in, const int* in_sizes, int n_in,
                              void* d_out, int out_size, void* d_ws, size_t ws_size,
                              hipStream_t stream) {
  const float* x     = (const float*)d_in[0];
  const float* h0    = (const float*)d_in[1];
  const float* c0    = (const float*)d_in[2];
  const float* W_ih  = (const float*)d_in[3];
  const float* W_hh  = (const float*)d_in[4];
  const float* bias  = (const float*)d_in[5];
  const float* W_out = (const float*)d_in[6];
  const float* b_out = (const float*)d_in[7];
  float* out = (float*)d_out;
  unsigned int* ws = (unsigned int*)d_ws;

  const bool pathA = (ws_size >= NEED_A_BYTES);
  const int total = pathA ? TOTAL_A : TOTAL_B;
  hipLaunchKernelGGL(prep_weights, dim3((total + 255)/256), dim3(256), 0, stream,
                     W_hh, W_ih, W_out, ws, pathA ? 1 : 0, total);
  if (pathA) {
    float* xwp = (float*)(ws + OFF_XW);
    hipLaunchKernelGGL(xw_precompute, dim3(SEQ*BATCH/128), dim3(256), 0, stream,
                       x, bias, ws + OFF_WIHRM, xwp);
    hipLaunchKernelGGL(lstm_scan<true>, dim3(BATCH), dim3(512), 0, stream,
                       x, h0, c0, bias, b_out, ws, xwp, out);
  } else {
    hipLaunchKernelGGL(lstm_scan<false>, dim3(BATCH), dim3(512), 0, stream,
                       x, h0, c0, bias, b_out, ws, (const float*)ws, out);
  }
}